// Round 12
// baseline (226.552 us; speedup 1.0000x reference)
//
#include <hip/hip_runtime.h>
#include <cmath>

#define TPB   128                 // threads per block (2 waves); each thread owns 4 cols
#define TH    16                  // output rows per block tile (22 input rows)
#define WID   512
#define HEI   512
#define NIMG  64
#define NTILE (HEI / TH)          // 32
#define NBLK  (NIMG * NTILE)      // 2048
#define LROW  520                 // 4 zero-pad | 512 cols | 4 zero-pad

// LEDGER law (R7-R11): __launch_bounds__(TPB,N) hard-caps VGPRs at 256/N:
// (,8)->32, (,4)->64, (,2)->128. Every spill (R2,R3,R7,R9,R10,R11 WRITE_SIZE
// 80-830MB) was the cap strangling the allocator. R6 (56 VGPR, 52.8us) only
// survived because it fit under the cap. The async-LDS structure needs ~135
// VGPR naturally (R11 spilled AT 128). R12 = R11 with NO launch_bounds:
// allocator free -> no spill -> ~3 waves/SIMD -> staging latency hidden by
// one stage of compute between global_load_lds issue and barrier drain.

typedef _Float16 h2 __attribute__((ext_vector_type(2)));

struct GW { unsigned int wh[7]; };   // f16 weight broadcast pairs (lo==hi)

__device__ __forceinline__ h2 pkrtz(float a, float b) {
    return __builtin_bit_cast(h2, __builtin_amdgcn_cvt_pkrtz(a, b));
}
__device__ __forceinline__ h2 fma2(h2 a, h2 b, h2 c) { return __builtin_elementwise_fma(a, b, c); }

// Stage input row gy into LDS buffer (interior base dstP/dstT = &lds[buf][f][4]).
// In-range: async global->LDS, 16B/lane, wave w covers cols 256w..256w+255.
// Out-of-range (SAME zero padding): ds_write zeros. Branch is block-uniform.
__device__ __forceinline__ void stage_row(int gy, int m,
                                          float* dstP, float* dstT,
                                          const float* __restrict__ pb,
                                          const float* __restrict__ tb)
{
    if (gy >= 0 && gy < HEI) {
        const int w = (m >> 6) << 8;            // wave column base: 0 or 256
        const float* ps = pb + (size_t)gy * WID + w + ((m & 63) << 2);
        const float* ts = tb + (size_t)gy * WID + w + ((m & 63) << 2);
        __builtin_amdgcn_global_load_lds(
            (const __attribute__((address_space(1))) void*)ps,
            (__attribute__((address_space(3))) void*)(dstP + w), 16, 0, 0);
        __builtin_amdgcn_global_load_lds(
            (const __attribute__((address_space(1))) void*)ts,
            (__attribute__((address_space(3))) void*)(dstT + w), 16, 0, 0);
    } else {
        const float4 z = make_float4(0.f, 0.f, 0.f, 0.f);
        *(float4*)(dstP + 4 * m) = z;
        *(float4*)(dstT + 4 * m) = z;
    }
}

// One input-row stage. Barrier first (drains row IY's staging load — compiler
// emits vmcnt(0) before s_barrier — and protects buf NXT from overwrite while
// stage IY-1 readers finish). Then issue row IY+1 staging, ds_read row IY,
// H-blur packed fields {A=blur(s),B=blur(d),S=blur(s^2),T=blur(d^2)} into
// ring slot IY%7; from IY>=6 V-blur + SSIM (f32).
template <int IY, bool DOLOAD>
__device__ __forceinline__ void ssim_stage(
    int oy0, int m,
    const float* __restrict__ pb, const float* __restrict__ tb,
    float (&lds)[2][2][LROW],
    const h2 (&w2)[7],
    h2 (&ring)[7][8],
    float& acc)
{
    constexpr int SL  = IY % 7;
    constexpr int CUR = IY & 1;
    constexpr int NXT = CUR ^ 1;

    __syncthreads();

    if constexpr (DOLOAD)
        stage_row(oy0 - 3 + IY + 1, m, &lds[NXT][0][4], &lds[NXT][1][4], pb, tb);

    // cols c0-4 .. c0+7 live at interior indices 4m .. 4m+11 (16B aligned)
    const float4 p0 = *(const float4*)&lds[CUR][0][4 * m + 0];
    const float4 p1 = *(const float4*)&lds[CUR][0][4 * m + 4];
    const float4 p2 = *(const float4*)&lds[CUR][0][4 * m + 8];
    const float4 t0 = *(const float4*)&lds[CUR][1][4 * m + 0];
    const float4 t1 = *(const float4*)&lds[CUR][1][4 * m + 4];
    const float4 t2 = *(const float4*)&lds[CUR][1][4 * m + 8];

    float pa[12], ta[12];
    pa[0]=p0.x; pa[1]=p0.y; pa[2]=p0.z; pa[3]=p0.w;
    pa[4]=p1.x; pa[5]=p1.y; pa[6]=p1.z; pa[7]=p1.w;
    pa[8]=p2.x; pa[9]=p2.y; pa[10]=p2.z; pa[11]=p2.w;
    ta[0]=t0.x; ta[1]=t0.y; ta[2]=t0.z; ta[3]=t0.w;
    ta[4]=t1.x; ta[5]=t1.y; ta[6]=t1.z; ta[7]=t1.w;
    ta[8]=t2.x; ta[9]=t2.y; ta[10]=t2.z; ta[11]=t2.w;

    // window value k = column (c0 - 3 + k); output col c uses k = c..c+6
    float ws[10], wd[10];
#pragma unroll
    for (int k = 0; k < 10; ++k) {
        ws[k] = pa[k + 1] + ta[k + 1];
        wd[k] = pa[k + 1] - ta[k + 1];
    }

    h2 W[9];   // packed sliding pairs W[k] = (w[k], w[k+1]); col-pair cp uses W[2cp..2cp+6]

    // field A = blur(s)
#pragma unroll
    for (int k = 0; k < 9; ++k) W[k] = pkrtz(ws[k], ws[k + 1]);
#pragma unroll
    for (int cp = 0; cp < 2; ++cp) {
        h2 a = w2[0] * W[2 * cp];
#pragma unroll
        for (int i = 1; i < 7; ++i) a = fma2(w2[i], W[2 * cp + i], a);
        ring[SL][0 + cp] = a;
    }
    // field S = blur(s^2)
#pragma unroll
    for (int k = 0; k < 9; ++k) W[k] = W[k] * W[k];
#pragma unroll
    for (int cp = 0; cp < 2; ++cp) {
        h2 a = w2[0] * W[2 * cp];
#pragma unroll
        for (int i = 1; i < 7; ++i) a = fma2(w2[i], W[2 * cp + i], a);
        ring[SL][4 + cp] = a;
    }
    // field B = blur(d)
#pragma unroll
    for (int k = 0; k < 9; ++k) W[k] = pkrtz(wd[k], wd[k + 1]);
#pragma unroll
    for (int cp = 0; cp < 2; ++cp) {
        h2 a = w2[0] * W[2 * cp];
#pragma unroll
        for (int i = 1; i < 7; ++i) a = fma2(w2[i], W[2 * cp + i], a);
        ring[SL][2 + cp] = a;
    }
    // field T = blur(d^2)
#pragma unroll
    for (int k = 0; k < 9; ++k) W[k] = W[k] * W[k];
#pragma unroll
    for (int cp = 0; cp < 2; ++cp) {
        h2 a = w2[0] * W[2 * cp];
#pragma unroll
        for (int i = 1; i < 7; ++i) a = fma2(w2[i], W[2 * cp + i], a);
        ring[SL][6 + cp] = a;
    }

    if constexpr (IY >= 6) {
        const float C1 = 1e-4f, C2 = 9e-4f;
#pragma unroll
        for (int cp = 0; cp < 2; ++cp) {
            h2 vA = w2[0] * ring[(SL + 1) % 7][0 + cp];
            h2 vB = w2[0] * ring[(SL + 1) % 7][2 + cp];
            h2 vS = w2[0] * ring[(SL + 1) % 7][4 + cp];
            h2 vT = w2[0] * ring[(SL + 1) % 7][6 + cp];
#pragma unroll
            for (int j = 1; j < 7; ++j) {
                const int sl = (SL + 1 + j) % 7;   // compile-time
                vA = fma2(w2[j], ring[sl][0 + cp], vA);
                vB = fma2(w2[j], ring[sl][2 + cp], vB);
                vS = fma2(w2[j], ring[sl][4 + cp], vS);
                vT = fma2(w2[j], ring[sl][6 + cp], vT);
            }
#pragma unroll
            for (int e = 0; e < 2; ++e) {
                const float fA = (float)vA[e], fB = (float)vB[e];
                const float fS = (float)vS[e], fT = (float)vT[e];
                const float A2 = fA * fA, B2 = fB * fB;
                const float muct2 = 0.5f * (A2 - B2);   // 2*mu_p*mu_t
                const float muss  = 0.5f * (A2 + B2);   // mu_p^2 + mu_t^2
                const float ptb2  = 0.5f * (fS - fT);   // 2*blur(p*t)
                const float ssb   = 0.5f * (fS + fT);   // blur(p^2 + t^2)
                const float num = (muct2 + C1) * (ptb2 - muct2 + C2);
                const float den = (muss + C1) * (ssb - muss + C2);
                acc += num * __builtin_amdgcn_rcpf(den);
            }
        }
    }
}

__global__
void ssim_main_k(const float* __restrict__ pred,
                 const float* __restrict__ targ,
                 float* __restrict__ partial,   // NBLK floats (d_ws), or null
                 float* __restrict__ outacc,    // fallback atomic accumulator
                 GW gw)
{
    __shared__ float lds[2][2][LROW];
    __shared__ float wpart[TPB / 64];

    const int m    = threadIdx.x;
    const int bid  = blockIdx.x;
    const int img  = bid >> 5;            // NTILE == 32
    const int tile = bid & (NTILE - 1);
    const int oy0  = tile * TH;

    h2 w2[7];
#pragma unroll
    for (int j = 0; j < 7; ++j) w2[j] = __builtin_bit_cast(h2, gw.wh[j]);

    const size_t ioff = (size_t)img * (WID * HEI);
    const float* pb = pred + ioff;
    const float* tb = targ + ioff;

    // zero the 4-float column pads (stay zero forever: staging writes interior only)
    if (m < 32) {
        const int b = m >> 4, f = (m >> 3) & 1, side = (m >> 2) & 1, j = m & 3;
        lds[b][f][side ? 516 + j : j] = 0.f;
    }
    // prologue: stage first row (oy0-3) into buf 0; stage<0>'s barrier makes it visible
    stage_row(oy0 - 3, m, &lds[0][0][4], &lds[0][1][4], pb, tb);

    h2 ring[7][8];   // [slot][field*2 + colpair]; fields A,B,S,T
    float acc = 0.f;

    // 22 input rows; buffer parity = IY&1; ring slot = IY%7 (all compile-time)
    ssim_stage< 0, true >(oy0, m, pb, tb, lds, w2, ring, acc);
    ssim_stage< 1, true >(oy0, m, pb, tb, lds, w2, ring, acc);
    ssim_stage< 2, true >(oy0, m, pb, tb, lds, w2, ring, acc);
    ssim_stage< 3, true >(oy0, m, pb, tb, lds, w2, ring, acc);
    ssim_stage< 4, true >(oy0, m, pb, tb, lds, w2, ring, acc);
    ssim_stage< 5, true >(oy0, m, pb, tb, lds, w2, ring, acc);
    ssim_stage< 6, true >(oy0, m, pb, tb, lds, w2, ring, acc);
    ssim_stage< 7, true >(oy0, m, pb, tb, lds, w2, ring, acc);
    ssim_stage< 8, true >(oy0, m, pb, tb, lds, w2, ring, acc);
    ssim_stage< 9, true >(oy0, m, pb, tb, lds, w2, ring, acc);
    ssim_stage<10, true >(oy0, m, pb, tb, lds, w2, ring, acc);
    ssim_stage<11, true >(oy0, m, pb, tb, lds, w2, ring, acc);
    ssim_stage<12, true >(oy0, m, pb, tb, lds, w2, ring, acc);
    ssim_stage<13, true >(oy0, m, pb, tb, lds, w2, ring, acc);
    ssim_stage<14, true >(oy0, m, pb, tb, lds, w2, ring, acc);
    ssim_stage<15, true >(oy0, m, pb, tb, lds, w2, ring, acc);
    ssim_stage<16, true >(oy0, m, pb, tb, lds, w2, ring, acc);
    ssim_stage<17, true >(oy0, m, pb, tb, lds, w2, ring, acc);
    ssim_stage<18, true >(oy0, m, pb, tb, lds, w2, ring, acc);
    ssim_stage<19, true >(oy0, m, pb, tb, lds, w2, ring, acc);
    ssim_stage<20, true >(oy0, m, pb, tb, lds, w2, ring, acc);
    ssim_stage<21, false>(oy0, m, pb, tb, lds, w2, ring, acc);

    // block reduction: wave shfl tree, then cross-wave via LDS
#pragma unroll
    for (int off = 32; off > 0; off >>= 1)
        acc += __shfl_down(acc, off, 64);
    __syncthreads();
    if ((m & 63) == 0) wpart[m >> 6] = acc;
    __syncthreads();
    if (m == 0) {
        const float tot = wpart[0] + wpart[1];
        if (partial) partial[bid] = tot;
        else atomicAdd(outacc, tot);
    }
}

__global__ void ssim_finalize_k(const float* __restrict__ partial,
                                float* __restrict__ out, int usews)
{
    const float invN = 1.0f / (float)((size_t)NIMG * WID * HEI);
    if (usews) {
        float s = 0.f;
        for (int i = threadIdx.x; i < NBLK; i += 256) s += partial[i];
#pragma unroll
        for (int off = 32; off > 0; off >>= 1) s += __shfl_down(s, off, 64);
        __shared__ float wp[4];
        if ((threadIdx.x & 63) == 0) wp[threadIdx.x >> 6] = s;
        __syncthreads();
        if (threadIdx.x == 0) out[0] = 1.0f - (wp[0] + wp[1] + wp[2] + wp[3]) * invN;
    } else {
        if (threadIdx.x == 0) out[0] = 1.0f - out[0] * invN;
    }
}

// host f32 -> f16 bits, round-to-nearest-even (weights are normal, positive)
static unsigned short f32_to_f16(float f) {
    union { float f; unsigned int u; } c; c.f = f;
    const unsigned int u = c.u;
    const int exp = (int)((u >> 23) & 0xFF) - 127 + 15;
    const unsigned int man = u & 0x7FFFFFu;
    if (exp <= 0) return 0;
    unsigned int base = ((unsigned int)exp << 10) | (man >> 13);
    const unsigned int rem = man & 0x1FFFu;
    base += (rem > 0x1000u) || (rem == 0x1000u && (base & 1u));
    return (unsigned short)base;
}
static float f16_to_f32(unsigned short h) {
    const int exp = (h >> 10) & 0x1F;
    const unsigned int man = h & 0x3FFu;
    if (exp == 0) return 0.f;
    union { unsigned int u; float f; } c;
    c.u = ((unsigned int)(exp - 15 + 127) << 23) | (man << 13);
    return c.f;
}

extern "C" void kernel_launch(void* const* d_in, const int* in_sizes, int n_in,
                              void* d_out, int out_size, void* d_ws, size_t ws_size,
                              hipStream_t stream)
{
    const float* pred = (const float*)d_in[0];
    const float* targ = (const float*)d_in[1];
    float* out = (float*)d_out;

    GW gw;
    {
        double g[7], s = 0.0;
        for (int i = 0; i < 7; ++i) {
            const double c = (double)(i - 3);
            g[i] = exp(-c * c / (2.0 * 1.5 * 1.5));
            s += g[i];
        }
        unsigned short h16[7];
        for (int i = 0; i < 7; ++i) h16[i] = f32_to_f16((float)(g[i] / s));
        // renormalize so the f16 weights sum as close to 1.0 as representable:
        // center tap = round_f16(1 - sum(others)) kills the systematic bias.
        float so = 0.f;
        for (int i = 0; i < 7; ++i) if (i != 3) so += f16_to_f32(h16[i]);
        h16[3] = f32_to_f16(1.0f - so);
        for (int i = 0; i < 7; ++i)
            gw.wh[i] = (unsigned int)h16[i] | ((unsigned int)h16[i] << 16);
    }

    const bool usews = (ws_size >= NBLK * sizeof(float));
    float* partial = usews ? (float*)d_ws : nullptr;
    if (!usews) (void)hipMemsetAsync(d_out, 0, sizeof(float), stream);

    ssim_main_k<<<NBLK, TPB, 0, stream>>>(pred, targ, partial, out, gw);
    ssim_finalize_k<<<1, 256, 0, stream>>>(partial, out, usews ? 1 : 0);
}

// Round 13
// 107.619 us; speedup vs baseline: 2.1051x; 2.1051x over previous
//
#include <hip/hip_runtime.h>
#include <cmath>

#define TPB   128                 // threads per block (2 waves); each thread owns 4 cols
#define TH    16                  // output rows per block tile (22 input rows)
#define WID   512
#define HEI   512
#define NIMG  64
#define NTILE (HEI / TH)          // 32
#define NBLK  (NIMG * NTILE)      // 2048

// LEDGER law (R7-R12): __launch_bounds__(TPB,N) hard-caps VGPRs at 256/N:
// (,8)->32, (,4)->64, DEFAULT(no bounds, LDS kernel)->64, (,2)->128, (,1)->256.
// Every spill (R2,R3,R7,R9,R10,R11,R12: WRITE_SIZE 80-830MB) was a cap
// strangling the allocator, never the structure's true need. R6 (56 VGPR,
// 52.8us best) fit under its cap. R13 = R9's register-prefetch structure
// (no LDS, no barriers, no bank conflicts) finally UNSTRANGLED via (,1):
// natural ~145 VGPR, 2 waves/SIMD, depth-1 prefetch hides the ~200-300cy
// L3-warm load latency under ~380cy of stage compute within each wave.

typedef _Float16 h2 __attribute__((ext_vector_type(2)));

struct GW { unsigned int wh[7]; };   // f16 weight broadcast pairs (lo==hi), SGPR-resident

struct RowBuf { float pa[12]; float ta[12]; };

__device__ __forceinline__ h2 pkrtz(float a, float b) {
    return __builtin_bit_cast(h2, __builtin_amdgcn_cvt_pkrtz(a, b));
}
__device__ __forceinline__ h2 fma2(h2 a, h2 b, h2 c) { return __builtin_elementwise_fma(a, b, c); }

// Load input row gy (f32): cols c0-4 .. c0+7 of pred and targ, zero outside.
__device__ __forceinline__ void loadrow(int gy, int m, int c0, int clm, int clp,
                                        const float* __restrict__ pb,
                                        const float* __restrict__ tb,
                                        RowBuf& b)
{
    if (gy >= 0 && gy < HEI) {
        const float* pr = pb + (size_t)gy * WID;
        const float* tr = tb + (size_t)gy * WID;
        float4 v0 = *(const float4*)(pr + clm);
        float4 v1 = *(const float4*)(pr + c0);
        float4 v2 = *(const float4*)(pr + clp);
        float4 u0 = *(const float4*)(tr + clm);
        float4 u1 = *(const float4*)(tr + c0);
        float4 u2 = *(const float4*)(tr + clp);
        if (m == 0)       { v0 = make_float4(0.f,0.f,0.f,0.f); u0 = make_float4(0.f,0.f,0.f,0.f); }
        if (m == TPB - 1) { v2 = make_float4(0.f,0.f,0.f,0.f); u2 = make_float4(0.f,0.f,0.f,0.f); }
        b.pa[0]=v0.x; b.pa[1]=v0.y; b.pa[2]=v0.z; b.pa[3]=v0.w;
        b.pa[4]=v1.x; b.pa[5]=v1.y; b.pa[6]=v1.z; b.pa[7]=v1.w;
        b.pa[8]=v2.x; b.pa[9]=v2.y; b.pa[10]=v2.z; b.pa[11]=v2.w;
        b.ta[0]=u0.x; b.ta[1]=u0.y; b.ta[2]=u0.z; b.ta[3]=u0.w;
        b.ta[4]=u1.x; b.ta[5]=u1.y; b.ta[6]=u1.z; b.ta[7]=u1.w;
        b.ta[8]=u2.x; b.ta[9]=u2.y; b.ta[10]=u2.z; b.ta[11]=u2.w;
    } else {
#pragma unroll
        for (int k = 0; k < 12; ++k) { b.pa[k] = 0.f; b.ta[k] = 0.f; }
    }
}

// One input-row stage. cur holds row (oy0-3+IY) raw f32 (loaded previously);
// first issue the prefetch of row IY+1 into nxt (completes under this stage's
// compute — compiler places the waitcnt before nxt's first USE next stage),
// then H-blur packed fields {A=blur(s),B=blur(d),S=blur(s^2),T=blur(d^2)}
// into ring slot IY%7; from IY>=6 V-blur + SSIM (f32).
template <int IY, bool DOLOAD>
__device__ __forceinline__ void ssim_stage(
    int oy0, int m, int c0, int clm, int clp,
    const float* __restrict__ pb, const float* __restrict__ tb,
    const h2 (&w2)[7],
    RowBuf& cur, RowBuf& nxt,
    h2 (&ring)[7][8],
    float& acc)
{
    constexpr int SL = IY % 7;

    if constexpr (DOLOAD) loadrow(oy0 - 3 + IY + 1, m, c0, clm, clp, pb, tb, nxt);

    // window value k = column (c0 - 3 + k); output col c uses k = c..c+6
    float ws[10], wd[10];
#pragma unroll
    for (int k = 0; k < 10; ++k) {
        ws[k] = cur.pa[k + 1] + cur.ta[k + 1];
        wd[k] = cur.pa[k + 1] - cur.ta[k + 1];
    }

    h2 W[9];   // packed sliding pairs W[k] = (w[k], w[k+1]); col-pair cp uses W[2cp..2cp+6]

    // field A = blur(s)
#pragma unroll
    for (int k = 0; k < 9; ++k) W[k] = pkrtz(ws[k], ws[k + 1]);
#pragma unroll
    for (int cp = 0; cp < 2; ++cp) {
        h2 a = w2[0] * W[2 * cp];
#pragma unroll
        for (int i = 1; i < 7; ++i) a = fma2(w2[i], W[2 * cp + i], a);
        ring[SL][0 + cp] = a;
    }
    // field S = blur(s^2)
#pragma unroll
    for (int k = 0; k < 9; ++k) W[k] = W[k] * W[k];
#pragma unroll
    for (int cp = 0; cp < 2; ++cp) {
        h2 a = w2[0] * W[2 * cp];
#pragma unroll
        for (int i = 1; i < 7; ++i) a = fma2(w2[i], W[2 * cp + i], a);
        ring[SL][4 + cp] = a;
    }
    // field B = blur(d)
#pragma unroll
    for (int k = 0; k < 9; ++k) W[k] = pkrtz(wd[k], wd[k + 1]);
#pragma unroll
    for (int cp = 0; cp < 2; ++cp) {
        h2 a = w2[0] * W[2 * cp];
#pragma unroll
        for (int i = 1; i < 7; ++i) a = fma2(w2[i], W[2 * cp + i], a);
        ring[SL][2 + cp] = a;
    }
    // field T = blur(d^2)
#pragma unroll
    for (int k = 0; k < 9; ++k) W[k] = W[k] * W[k];
#pragma unroll
    for (int cp = 0; cp < 2; ++cp) {
        h2 a = w2[0] * W[2 * cp];
#pragma unroll
        for (int i = 1; i < 7; ++i) a = fma2(w2[i], W[2 * cp + i], a);
        ring[SL][6 + cp] = a;
    }

    if constexpr (IY >= 6) {
        const float C1 = 1e-4f, C2 = 9e-4f;
#pragma unroll
        for (int cp = 0; cp < 2; ++cp) {
            h2 vA = w2[0] * ring[(SL + 1) % 7][0 + cp];
            h2 vB = w2[0] * ring[(SL + 1) % 7][2 + cp];
            h2 vS = w2[0] * ring[(SL + 1) % 7][4 + cp];
            h2 vT = w2[0] * ring[(SL + 1) % 7][6 + cp];
#pragma unroll
            for (int j = 1; j < 7; ++j) {
                const int sl = (SL + 1 + j) % 7;   // compile-time
                vA = fma2(w2[j], ring[sl][0 + cp], vA);
                vB = fma2(w2[j], ring[sl][2 + cp], vB);
                vS = fma2(w2[j], ring[sl][4 + cp], vS);
                vT = fma2(w2[j], ring[sl][6 + cp], vT);
            }
#pragma unroll
            for (int e = 0; e < 2; ++e) {
                const float fA = (float)vA[e], fB = (float)vB[e];
                const float fS = (float)vS[e], fT = (float)vT[e];
                const float A2 = fA * fA, B2 = fB * fB;
                const float muct2 = 0.5f * (A2 - B2);   // 2*mu_p*mu_t
                const float muss  = 0.5f * (A2 + B2);   // mu_p^2 + mu_t^2
                const float ptb2  = 0.5f * (fS - fT);   // 2*blur(p*t)
                const float ssb   = 0.5f * (fS + fT);   // blur(p^2 + t^2)
                const float num = (muct2 + C1) * (ptb2 - muct2 + C2);
                const float den = (muss + C1) * (ssb - muss + C2);
                acc += num * __builtin_amdgcn_rcpf(den);
            }
        }
    }
}

__global__ __launch_bounds__(TPB, 1)
void ssim_main_k(const float* __restrict__ pred,
                 const float* __restrict__ targ,
                 float* __restrict__ partial,   // NBLK floats (d_ws), or null
                 float* __restrict__ outacc,    // fallback atomic accumulator
                 GW gw)
{
    const int m    = threadIdx.x;
    const int bid  = blockIdx.x;
    const int img  = bid >> 5;            // NTILE == 32
    const int tile = bid & (NTILE - 1);
    const int oy0  = tile * TH;

    h2 w2[7];
#pragma unroll
    for (int j = 0; j < 7; ++j) w2[j] = __builtin_bit_cast(h2, gw.wh[j]);

    const size_t ioff = (size_t)img * (WID * HEI);
    const float* pb = pred + ioff;
    const float* tb = targ + ioff;

    const int c0  = 4 * m;
    const int clm = (m == 0) ? 0 : (c0 - 4);          // clamped (value zeroed)
    const int clp = (m == TPB - 1) ? c0 : (c0 + 4);   // clamped (value zeroed)

    h2 ring[7][8];   // [slot][field*2 + colpair]; fields A,B,S,T
    RowBuf rb0, rb1;
    float acc = 0.f;

    loadrow(oy0 - 3, m, c0, clm, clp, pb, tb, rb0);

    // 22 input rows; cur = rb[IY&1], nxt = rb[(IY+1)&1]; ring slot = IY%7 static
    ssim_stage< 0, true >(oy0, m, c0, clm, clp, pb, tb, w2, rb0, rb1, ring, acc);
    ssim_stage< 1, true >(oy0, m, c0, clm, clp, pb, tb, w2, rb1, rb0, ring, acc);
    ssim_stage< 2, true >(oy0, m, c0, clm, clp, pb, tb, w2, rb0, rb1, ring, acc);
    ssim_stage< 3, true >(oy0, m, c0, clm, clp, pb, tb, w2, rb1, rb0, ring, acc);
    ssim_stage< 4, true >(oy0, m, c0, clm, clp, pb, tb, w2, rb0, rb1, ring, acc);
    ssim_stage< 5, true >(oy0, m, c0, clm, clp, pb, tb, w2, rb1, rb0, ring, acc);
    ssim_stage< 6, true >(oy0, m, c0, clm, clp, pb, tb, w2, rb0, rb1, ring, acc);
    ssim_stage< 7, true >(oy0, m, c0, clm, clp, pb, tb, w2, rb1, rb0, ring, acc);
    ssim_stage< 8, true >(oy0, m, c0, clm, clp, pb, tb, w2, rb0, rb1, ring, acc);
    ssim_stage< 9, true >(oy0, m, c0, clm, clp, pb, tb, w2, rb1, rb0, ring, acc);
    ssim_stage<10, true >(oy0, m, c0, clm, clp, pb, tb, w2, rb0, rb1, ring, acc);
    ssim_stage<11, true >(oy0, m, c0, clm, clp, pb, tb, w2, rb1, rb0, ring, acc);
    ssim_stage<12, true >(oy0, m, c0, clm, clp, pb, tb, w2, rb0, rb1, ring, acc);
    ssim_stage<13, true >(oy0, m, c0, clm, clp, pb, tb, w2, rb1, rb0, ring, acc);
    ssim_stage<14, true >(oy0, m, c0, clm, clp, pb, tb, w2, rb0, rb1, ring, acc);
    ssim_stage<15, true >(oy0, m, c0, clm, clp, pb, tb, w2, rb1, rb0, ring, acc);
    ssim_stage<16, true >(oy0, m, c0, clm, clp, pb, tb, w2, rb0, rb1, ring, acc);
    ssim_stage<17, true >(oy0, m, c0, clm, clp, pb, tb, w2, rb1, rb0, ring, acc);
    ssim_stage<18, true >(oy0, m, c0, clm, clp, pb, tb, w2, rb0, rb1, ring, acc);
    ssim_stage<19, true >(oy0, m, c0, clm, clp, pb, tb, w2, rb1, rb0, ring, acc);
    ssim_stage<20, true >(oy0, m, c0, clm, clp, pb, tb, w2, rb0, rb1, ring, acc);
    ssim_stage<21, false>(oy0, m, c0, clm, clp, pb, tb, w2, rb1, rb0, ring, acc);

    // block reduction: wave shfl tree, then cross-wave via LDS
#pragma unroll
    for (int off = 32; off > 0; off >>= 1)
        acc += __shfl_down(acc, off, 64);
    __shared__ float wpart[TPB / 64];
    if ((m & 63) == 0) wpart[m >> 6] = acc;
    __syncthreads();
    if (m == 0) {
        const float tot = wpart[0] + wpart[1];
        if (partial) partial[bid] = tot;
        else atomicAdd(outacc, tot);
    }
}

__global__ void ssim_finalize_k(const float* __restrict__ partial,
                                float* __restrict__ out, int usews)
{
    const float invN = 1.0f / (float)((size_t)NIMG * WID * HEI);
    if (usews) {
        float s = 0.f;
        for (int i = threadIdx.x; i < NBLK; i += 256) s += partial[i];
#pragma unroll
        for (int off = 32; off > 0; off >>= 1) s += __shfl_down(s, off, 64);
        __shared__ float wp[4];
        if ((threadIdx.x & 63) == 0) wp[threadIdx.x >> 6] = s;
        __syncthreads();
        if (threadIdx.x == 0) out[0] = 1.0f - (wp[0] + wp[1] + wp[2] + wp[3]) * invN;
    } else {
        if (threadIdx.x == 0) out[0] = 1.0f - out[0] * invN;
    }
}

// host f32 -> f16 bits, round-to-nearest-even (weights are normal, positive)
static unsigned short f32_to_f16(float f) {
    union { float f; unsigned int u; } c; c.f = f;
    const unsigned int u = c.u;
    const int exp = (int)((u >> 23) & 0xFF) - 127 + 15;
    const unsigned int man = u & 0x7FFFFFu;
    if (exp <= 0) return 0;
    unsigned int base = ((unsigned int)exp << 10) | (man >> 13);
    const unsigned int rem = man & 0x1FFFu;
    base += (rem > 0x1000u) || (rem == 0x1000u && (base & 1u));
    return (unsigned short)base;
}
static float f16_to_f32(unsigned short h) {
    const int exp = (h >> 10) & 0x1F;
    const unsigned int man = h & 0x3FFu;
    if (exp == 0) return 0.f;
    union { unsigned int u; float f; } c;
    c.u = ((unsigned int)(exp - 15 + 127) << 23) | (man << 13);
    return c.f;
}

extern "C" void kernel_launch(void* const* d_in, const int* in_sizes, int n_in,
                              void* d_out, int out_size, void* d_ws, size_t ws_size,
                              hipStream_t stream)
{
    const float* pred = (const float*)d_in[0];
    const float* targ = (const float*)d_in[1];
    float* out = (float*)d_out;

    GW gw;
    {
        double g[7], s = 0.0;
        for (int i = 0; i < 7; ++i) {
            const double c = (double)(i - 3);
            g[i] = exp(-c * c / (2.0 * 1.5 * 1.5));
            s += g[i];
        }
        unsigned short h16[7];
        for (int i = 0; i < 7; ++i) h16[i] = f32_to_f16((float)(g[i] / s));
        // renormalize so the f16 weights sum as close to 1.0 as representable:
        // center tap = round_f16(1 - sum(others)) kills the systematic bias.
        float so = 0.f;
        for (int i = 0; i < 7; ++i) if (i != 3) so += f16_to_f32(h16[i]);
        h16[3] = f32_to_f16(1.0f - so);
        for (int i = 0; i < 7; ++i)
            gw.wh[i] = (unsigned int)h16[i] | ((unsigned int)h16[i] << 16);
    }

    const bool usews = (ws_size >= NBLK * sizeof(float));
    float* partial = usews ? (float*)d_ws : nullptr;
    if (!usews) (void)hipMemsetAsync(d_out, 0, sizeof(float), stream);

    ssim_main_k<<<NBLK, TPB, 0, stream>>>(pred, targ, partial, out, gw);
    ssim_finalize_k<<<1, 256, 0, stream>>>(partial, out, usews ? 1 : 0);
}

// Round 14
// 50.070 us; speedup vs baseline: 4.5248x; 2.1494x over previous
//
#include <hip/hip_runtime.h>
#include <cmath>

#define TPB   128                 // threads per block (2 waves); each thread owns 4 cols
#define TH    16                  // output rows per block tile (22 input rows)
#define WID   512
#define HEI   512
#define NIMG  64
#define NTILE (HEI / TH)          // 32
#define NBLK  (NIMG * NTILE)      // 2048

// LEDGER (final structural conclusions):
//  - __launch_bounds__(TPB,N) hard-caps VGPR at 256/N; default(LDS kernel)=64.
//  - Register-resident prefetch (R2,R3,R9,R13) ALWAYS spills: compiler
//    inflates live ranges (R13: 224 VGPR + 147MB scratch at open cap).
//  - LDS async staging (R10-R12) needs ~135 VGPR -> spills at every cap.
//  - Only healthy shape: R6 (load-at-top, f16 ring, <=64 VGPR, TLP-only).
// R14 = R6 with (s,d)-per-column h2 packing: 10 pkrtz + 10 pk-mul instead
// of 18+18, transients 29->20 regs. Strictly less work, strictly less
// pressure, zero structural change.

typedef _Float16 h2 __attribute__((ext_vector_type(2)));

struct GW { unsigned int wh[7]; };   // f16 weight broadcast pairs (lo==hi), SGPR-resident

__device__ __forceinline__ h2 pkrtz(float a, float b) {
    return __builtin_bit_cast(h2, __builtin_amdgcn_cvt_pkrtz(a, b));
}
__device__ __forceinline__ h2 fma2(h2 a, h2 b, h2 c) { return __builtin_elementwise_fma(a, b, c); }

// One input-row stage: load row gy (f32), pack (s,d)=(p+t,p-t) per column
// into h2, square for (s^2,d^2); H-blur both packed fields into ring slot
// SL; when IY>=6 V-blur the ring + SSIM (f32).
template <int SL>
__device__ __forceinline__ void ssim_stage(
    int IY, int oy0, int m, int c0, int clm, int clp,
    const float* __restrict__ pb, const float* __restrict__ tb,
    const h2 (&w2)[7],
    h2 (&rAB)[7][4], h2 (&rST)[7][4],
    float& acc)
{
    const int gy = oy0 - 3 + IY;
    float pa[12], ta[12];
    if (gy >= 0 && gy < HEI) {
        const float* pr = pb + (size_t)gy * WID;
        const float* tr = tb + (size_t)gy * WID;
        float4 v0 = *(const float4*)(pr + clm);
        float4 v1 = *(const float4*)(pr + c0);
        float4 v2 = *(const float4*)(pr + clp);
        float4 u0 = *(const float4*)(tr + clm);
        float4 u1 = *(const float4*)(tr + c0);
        float4 u2 = *(const float4*)(tr + clp);
        if (m == 0)       { v0 = make_float4(0.f,0.f,0.f,0.f); u0 = make_float4(0.f,0.f,0.f,0.f); }
        if (m == TPB - 1) { v2 = make_float4(0.f,0.f,0.f,0.f); u2 = make_float4(0.f,0.f,0.f,0.f); }
        pa[0]=v0.x; pa[1]=v0.y; pa[2]=v0.z; pa[3]=v0.w;
        pa[4]=v1.x; pa[5]=v1.y; pa[6]=v1.z; pa[7]=v1.w;
        pa[8]=v2.x; pa[9]=v2.y; pa[10]=v2.z; pa[11]=v2.w;
        ta[0]=u0.x; ta[1]=u0.y; ta[2]=u0.z; ta[3]=u0.w;
        ta[4]=u1.x; ta[5]=u1.y; ta[6]=u1.z; ta[7]=u1.w;
        ta[8]=u2.x; ta[9]=u2.y; ta[10]=u2.z; ta[11]=u2.w;
    } else {
#pragma unroll
        for (int k = 0; k < 12; ++k) { pa[k] = 0.f; ta[k] = 0.f; }
    }

    // window col k = image column (c0 - 3 + k); output col c uses k = c..c+6
    h2 sd[10], sq[10];
#pragma unroll
    for (int k = 0; k < 10; ++k) {
        const float s = pa[k + 1] + ta[k + 1];
        const float d = pa[k + 1] - ta[k + 1];
        sd[k] = pkrtz(s, d);        // (s, d) packed per column
        sq[k] = sd[k] * sd[k];      // (s^2, d^2)
    }

    // H-blur both packed fields: 2 x 4 cols x 7 taps pk-fma
#pragma unroll
    for (int c = 0; c < 4; ++c) {
        h2 ab = w2[0] * sd[c];
        h2 st = w2[0] * sq[c];
#pragma unroll
        for (int i = 1; i < 7; ++i) {
            ab = fma2(w2[i], sd[c + i], ab);
            st = fma2(w2[i], sq[c + i], st);
        }
        rAB[SL][c] = ab;
        rST[SL][c] = st;
    }

    if (IY >= 6) {
        const float C1 = 1e-4f, C2 = 9e-4f;
#pragma unroll
        for (int c = 0; c < 4; ++c) {
            h2 vAB = w2[0] * rAB[(SL + 1) % 7][c];
            h2 vST = w2[0] * rST[(SL + 1) % 7][c];
#pragma unroll
            for (int j = 1; j < 7; ++j) {
                const int sl = (SL + 1 + j) % 7;   // compile-time
                vAB = fma2(w2[j], rAB[sl][c], vAB);
                vST = fma2(w2[j], rST[sl][c], vST);
            }
            const float fA = (float)vAB[0], fB = (float)vAB[1];
            const float fS = (float)vST[0], fT = (float)vST[1];
            const float A2 = fA * fA, B2 = fB * fB;
            const float muct2 = 0.5f * (A2 - B2);   // 2*mu_p*mu_t
            const float muss  = 0.5f * (A2 + B2);   // mu_p^2 + mu_t^2
            const float ptb2  = 0.5f * (fS - fT);   // 2*blur(p*t)
            const float ssb   = 0.5f * (fS + fT);   // blur(p^2 + t^2)
            const float num = (muct2 + C1) * (ptb2 - muct2 + C2);
            const float den = (muss + C1) * (ssb - muss + C2);
            acc += num * __builtin_amdgcn_rcpf(den);
        }
    }
}

__global__ __launch_bounds__(TPB, 4)
void ssim_main_k(const float* __restrict__ pred,
                 const float* __restrict__ targ,
                 float* __restrict__ partial,   // NBLK floats (d_ws), or null
                 float* __restrict__ outacc,    // fallback atomic accumulator
                 GW gw)
{
    const int m    = threadIdx.x;
    const int bid  = blockIdx.x;
    const int img  = bid >> 5;            // NTILE == 32
    const int tile = bid & (NTILE - 1);
    const int oy0  = tile * TH;

    h2 w2[7];
#pragma unroll
    for (int j = 0; j < 7; ++j) w2[j] = __builtin_bit_cast(h2, gw.wh[j]);

    const size_t ioff = (size_t)img * (WID * HEI);
    const float* pb = pred + ioff;
    const float* tb = targ + ioff;

    const int c0  = 4 * m;
    const int clm = (m == 0) ? 0 : (c0 - 4);          // clamped (value zeroed)
    const int clp = (m == TPB - 1) ? c0 : (c0 + 4);   // clamped (value zeroed)

    h2 rAB[7][4], rST[7][4];    // ring: [slot][col], (A,B) and (S,T) packed
    float acc = 0.f;

    // 22 input rows = 3*7 + 1; groups of 7 so ring slot == IY % 7 is static
    for (int it = 0; it < 3; ++it) {
        const int base = it * 7;
        ssim_stage<0>(base + 0, oy0, m, c0, clm, clp, pb, tb, w2, rAB, rST, acc);
        ssim_stage<1>(base + 1, oy0, m, c0, clm, clp, pb, tb, w2, rAB, rST, acc);
        ssim_stage<2>(base + 2, oy0, m, c0, clm, clp, pb, tb, w2, rAB, rST, acc);
        ssim_stage<3>(base + 3, oy0, m, c0, clm, clp, pb, tb, w2, rAB, rST, acc);
        ssim_stage<4>(base + 4, oy0, m, c0, clm, clp, pb, tb, w2, rAB, rST, acc);
        ssim_stage<5>(base + 5, oy0, m, c0, clm, clp, pb, tb, w2, rAB, rST, acc);
        ssim_stage<6>(base + 6, oy0, m, c0, clm, clp, pb, tb, w2, rAB, rST, acc);
    }
    ssim_stage<0>(21, oy0, m, c0, clm, clp, pb, tb, w2, rAB, rST, acc);

    // block reduction: wave shfl tree, then cross-wave via LDS
#pragma unroll
    for (int off = 32; off > 0; off >>= 1)
        acc += __shfl_down(acc, off, 64);
    __shared__ float wpart[TPB / 64];
    if ((m & 63) == 0) wpart[m >> 6] = acc;
    __syncthreads();
    if (m == 0) {
        const float tot = wpart[0] + wpart[1];
        if (partial) partial[bid] = tot;
        else atomicAdd(outacc, tot);
    }
}

__global__ void ssim_finalize_k(const float* __restrict__ partial,
                                float* __restrict__ out, int usews)
{
    const float invN = 1.0f / (float)((size_t)NIMG * WID * HEI);
    if (usews) {
        float s = 0.f;
        for (int i = threadIdx.x; i < NBLK; i += 256) s += partial[i];
#pragma unroll
        for (int off = 32; off > 0; off >>= 1) s += __shfl_down(s, off, 64);
        __shared__ float wp[4];
        if ((threadIdx.x & 63) == 0) wp[threadIdx.x >> 6] = s;
        __syncthreads();
        if (threadIdx.x == 0) out[0] = 1.0f - (wp[0] + wp[1] + wp[2] + wp[3]) * invN;
    } else {
        if (threadIdx.x == 0) out[0] = 1.0f - out[0] * invN;
    }
}

// host f32 -> f16 bits, round-to-nearest-even (weights are normal, positive)
static unsigned short f32_to_f16(float f) {
    union { float f; unsigned int u; } c; c.f = f;
    const unsigned int u = c.u;
    const int exp = (int)((u >> 23) & 0xFF) - 127 + 15;
    const unsigned int man = u & 0x7FFFFFu;
    if (exp <= 0) return 0;
    unsigned int base = ((unsigned int)exp << 10) | (man >> 13);
    const unsigned int rem = man & 0x1FFFu;
    base += (rem > 0x1000u) || (rem == 0x1000u && (base & 1u));
    return (unsigned short)base;
}
static float f16_to_f32(unsigned short h) {
    const int exp = (h >> 10) & 0x1F;
    const unsigned int man = h & 0x3FFu;
    if (exp == 0) return 0.f;
    union { unsigned int u; float f; } c;
    c.u = ((unsigned int)(exp - 15 + 127) << 23) | (man << 13);
    return c.f;
}

extern "C" void kernel_launch(void* const* d_in, const int* in_sizes, int n_in,
                              void* d_out, int out_size, void* d_ws, size_t ws_size,
                              hipStream_t stream)
{
    const float* pred = (const float*)d_in[0];
    const float* targ = (const float*)d_in[1];
    float* out = (float*)d_out;

    GW gw;
    {
        double g[7], s = 0.0;
        for (int i = 0; i < 7; ++i) {
            const double c = (double)(i - 3);
            g[i] = exp(-c * c / (2.0 * 1.5 * 1.5));
            s += g[i];
        }
        unsigned short h16[7];
        for (int i = 0; i < 7; ++i) h16[i] = f32_to_f16((float)(g[i] / s));
        // renormalize so the f16 weights sum as close to 1.0 as representable:
        // center tap = round_f16(1 - sum(others)) kills the systematic bias.
        float so = 0.f;
        for (int i = 0; i < 7; ++i) if (i != 3) so += f16_to_f32(h16[i]);
        h16[3] = f32_to_f16(1.0f - so);
        for (int i = 0; i < 7; ++i)
            gw.wh[i] = (unsigned int)h16[i] | ((unsigned int)h16[i] << 16);
    }

    const bool usews = (ws_size >= NBLK * sizeof(float));
    float* partial = usews ? (float*)d_ws : nullptr;
    if (!usews) (void)hipMemsetAsync(d_out, 0, sizeof(float), stream);

    ssim_main_k<<<NBLK, TPB, 0, stream>>>(pred, targ, partial, out, gw);
    ssim_finalize_k<<<1, 256, 0, stream>>>(partial, out, usews ? 1 : 0);
}